// Round 1
// 223.863 us; speedup vs baseline: 1.3531x; 1.3531x over previous
//
#include <hip/hip_runtime.h>
#include <hip/hip_bf16.h>

typedef __attribute__((ext_vector_type(8))) short short8;
typedef __attribute__((ext_vector_type(4))) short short4v;
typedef __attribute__((ext_vector_type(4))) float floatx4;

constexpr int B = 4, L = 2048, H = 16, E = 64, D = 1024;
constexpr int QT = 128, KT = 64;
constexpr int STR = 72;   // prep LDS transpose stride (144 B rows, 16B-aligned)
constexpr float SCL_LOG2E = 0.125f * 1.4426950408889634f;  // 1/sqrt(64) * log2(e)

__device__ __forceinline__ short bf16_bits(float x) {
    __hip_bfloat16 b = __float2bfloat16(x);
    return *(const short*)&b;
}

__device__ __forceinline__ short8 packq8(float4 a, float4 c, float scl) {
    short8 r;
    r[0] = bf16_bits(a.x * scl); r[1] = bf16_bits(a.y * scl);
    r[2] = bf16_bits(a.z * scl); r[3] = bf16_bits(a.w * scl);
    r[4] = bf16_bits(c.x * scl); r[5] = bf16_bits(c.y * scl);
    r[6] = bf16_bits(c.z * scl); r[7] = bf16_bits(c.w * scl);
    return r;
}

// ---------------------------------------------------------------------------
// Prep: emit K and V^T per 64-s tile ALREADY IN MFMA-FRAGMENT ORDER so the
// main kernel's LDS staging and fragment reads are lane-linear (0 conflicts).
//
// K tile (8KB, 512x16B chunks): chunk f = (nt*2+h)*64 + quad*16 + c16
//   holds K[s = nt*16+c16][d = h*32 + quad*8 .. +8)
// V tile (8KB, 1024x8B chunks): chunk g = (st*4+dt)*64 + quad*16 + c16
//   holds V[s = st*16 + quad*4 .. +4)[d = dt*16 + c16]   (i.e. V^T 4-s runs)
// ---------------------------------------------------------------------------
__global__ __launch_bounds__(256)
void prep_kv(const float* __restrict__ K, const float* __restrict__ V,
             short* __restrict__ Kb, short* __restrict__ Vt)
{
    __shared__ __align__(16) short vt[64 * STR];
    const int tid = threadIdx.x;
    const int bh = blockIdx.x >> 5, kt = blockIdx.x & 31;
    const int b = bh >> 4, h = bh & 15;

    const float* Kp = K + ((size_t)(b * L + kt * 64)) * D + h * E;
    const float* Vp = V + ((size_t)(b * L + kt * 64)) * D + h * E;
    short* Kop = Kb + ((size_t)(bh * 32 + kt)) * 4096;
    short* Vop = Vt + ((size_t)(bh * 32 + kt)) * 4096;

    // ---- K: global fp32 -> bf16, fragment-ordered 16B chunks ----
    #pragma unroll
    for (int it = 0; it < 2; ++it) {
        int f = it * 256 + tid;
        int nt = f >> 7, hh = (f >> 6) & 1, qd = (f >> 4) & 3, cc = f & 15;
        int s = nt * 16 + cc, d0 = hh * 32 + qd * 8;
        const float* p = Kp + (size_t)s * D + d0;
        float4 x = *(const float4*)p;
        float4 y = *(const float4*)(p + 4);
        union { short sh[8]; uint4 u; } pk;
        pk.sh[0] = bf16_bits(x.x); pk.sh[1] = bf16_bits(x.y);
        pk.sh[2] = bf16_bits(x.z); pk.sh[3] = bf16_bits(x.w);
        pk.sh[4] = bf16_bits(y.x); pk.sh[5] = bf16_bits(y.y);
        pk.sh[6] = bf16_bits(y.z); pk.sh[7] = bf16_bits(y.w);
        *(uint4*)(Kop + (size_t)f * 8) = pk.u;
    }

    // ---- V phase 1: transpose into LDS vt[d][s] ----
    #pragma unroll
    for (int p = 0; p < 4; ++p) {
        int idx = p * 256 + tid;
        int s = idx >> 4, c4 = (idx & 15) * 4;
        float4 g = *(const float4*)(Vp + (size_t)s * D + c4);
        vt[(c4 + 0) * STR + s] = bf16_bits(g.x);
        vt[(c4 + 1) * STR + s] = bf16_bits(g.y);
        vt[(c4 + 2) * STR + s] = bf16_bits(g.z);
        vt[(c4 + 3) * STR + s] = bf16_bits(g.w);
    }
    __syncthreads();

    // ---- V phase 2: fragment-ordered store (two 8B chunks -> one 16B) ----
    #pragma unroll
    for (int it = 0; it < 2; ++it) {
        int f16 = it * 256 + tid;
        int f8 = f16 * 2;                    // even -> pair shares (st,dt,quad)
        int st = f8 >> 8, dt = (f8 >> 6) & 3, qd = (f8 >> 4) & 3;
        int cA = f8 & 15;                    // even
        int dA = dt * 16 + cA, dB = dA + 1;
        int s0 = st * 16 + qd * 4;
        uint2 a = *(const uint2*)&vt[dA * STR + s0];
        uint2 c = *(const uint2*)&vt[dB * STR + s0];
        uint4 u; u.x = a.x; u.y = a.y; u.z = c.x; u.w = c.y;
        *(uint4*)(Vop + (size_t)f16 * 8) = u;
    }
}

// ---------------------------------------------------------------------------
// Main: 512 threads (8 waves x 16 q-rows), QT=128, paired q-tiles {15-p, p}.
// S^T = K*Q^T so P stays in registers (C-layout == 16x16x16 A-layout).
// LDS double-buffered, 1 barrier/tile; all LDS traffic lane-linear.
// ---------------------------------------------------------------------------
__global__ __launch_bounds__(512, 4)
void attn_fwd_p(const float* __restrict__ Q, const short* __restrict__ Kb,
                const short* __restrict__ Vt, float* __restrict__ O)
{
    __shared__ __align__(16) short k_s[2 * 4096];   // 2 x 8KB K tiles
    __shared__ __align__(16) short v_s[2 * 4096];   // 2 x 8KB V tiles

    const int tid  = threadIdx.x;
    const int wave = tid >> 6;          // 0..7, owns q-rows wave*16..+16
    const int lane = tid & 63;
    const int c16  = lane & 15;
    const int quad = lane >> 4;

    // 512 blocks = 64 bh x 8 pairs; all 8 pair-blocks of a head -> same XCD
    const int i  = (int)blockIdx.x;
    const int bh = ((i >> 6) << 3) | (i & 7);
    const int pr = (i >> 3) & 7;
    const int b  = bh >> 4;
    const int h  = bh & 15;

    const float* Qp  = Q  + ((size_t)b * L) * D + h * E;
    const short* Kbp = Kb + ((size_t)bh * 32) * 4096;
    const short* Vtp = Vt + ((size_t)bh * 32) * 4096;
    float*       Op  = O  + ((size_t)b * L) * D + h * E;

    for (int sub = 0; sub < 2; ++sub) {
        const int qt = (sub == 0) ? (15 - pr) : pr;   // heavy first
        const int q_base = qt * QT;
        const int n_tiles = 2 * qt + 2;
        const int m0 = q_base + wave * 16;            // this wave's first q-row

        // ---- Q fragments straight from global fp32 (scale*log2e folded) ----
        const float* qrow = Qp + (size_t)(q_base + wave * 16 + c16) * D + quad * 8;
        short8 qf0 = packq8(*(const float4*)(qrow),      *(const float4*)(qrow + 4),  SCL_LOG2E);
        short8 qf1 = packq8(*(const float4*)(qrow + 32), *(const float4*)(qrow + 36), SCL_LOG2E);

        // ---- prefetch tile 0, stage into buffer 0 ----
        uint4 kr = *(const uint4*)(Kbp + (size_t)tid * 8);
        uint4 vr = *(const uint4*)(Vtp + (size_t)tid * 8);
        __syncthreads();                         // prior sub done reading LDS
        *(uint4*)&k_s[tid * 8] = kr;
        *(uint4*)&v_s[tid * 8] = vr;

        floatx4 o[4];
        #pragma unroll
        for (int dt = 0; dt < 4; ++dt) o[dt] = (floatx4){0.f, 0.f, 0.f, 0.f};
        float lsum = 0.f;

        for (int t = 0; t < n_tiles; ++t) {
            __syncthreads();                     // buf[t&1] staged & prev reads done
            const short* kc = k_s + (t & 1) * 4096;
            const short* vc = v_s + (t & 1) * 4096;
            short* kn = k_s + ((t + 1) & 1) * 4096;
            short* vn = v_s + ((t + 1) & 1) * 4096;

            const bool more = (t + 1 < n_tiles);
            if (more) {
                const size_t nb = (size_t)(t + 1) * 4096 + (size_t)tid * 8;
                kr = *(const uint4*)(Kbp + nb);
                vr = *(const uint4*)(Vtp + nb);
            }

            if (t * 64 <= m0 + 15) {             // wave-uniform: any unmasked s?
                const bool diag = (t * 64 + 63 > m0);
                short4v pa[4];
                #pragma unroll
                for (int nt = 0; nt < 4; ++nt) {
                    short8 kb0 = *(const short8*)&kc[nt * 1024 + lane * 8];
                    short8 kb1 = *(const short8*)&kc[nt * 1024 + 512 + lane * 8];
                    floatx4 acc = (floatx4){0.f, 0.f, 0.f, 0.f};
                    acc = __builtin_amdgcn_mfma_f32_16x16x32_bf16(kb0, qf0, acc, 0, 0, 0);
                    acc = __builtin_amdgcn_mfma_f32_16x16x32_bf16(kb1, qf1, acc, 0, 0, 0);
                    // lane holds S^T[s = t*64+nt*16+quad*4+r][m = m0+c16]
                    if (diag) {
                        const int s0 = t * 64 + nt * 16 + quad * 4;
                        const int m  = m0 + c16;
                        #pragma unroll
                        for (int r = 0; r < 4; ++r)
                            if (s0 + r > m) acc[r] = -__builtin_inff();
                    }
                    #pragma unroll
                    for (int r = 0; r < 4; ++r) {
                        float p = exp2f(acc[r]);
                        lsum += p;
                        pa[nt][r] = bf16_bits(p);
                    }
                }
                // ---- O += P V via 16x16x16 (P regs already A-layout) ----
                #pragma unroll
                for (int st = 0; st < 4; ++st) {
                    #pragma unroll
                    for (int dt = 0; dt < 4; ++dt) {
                        short4v vb = *(const short4v*)&vc[(st * 4 + dt) * 256 + lane * 4];
                        o[dt] = __builtin_amdgcn_mfma_f32_16x16x16bf16_1k(pa[st], vb, o[dt], 0, 0, 0);
                    }
                }
            }

            if (more) {                          // stage t+1 into the other buffer
                *(uint4*)&kn[tid * 8] = kr;
                *(uint4*)&vn[tid * 8] = vr;
            }
        }

        // ---- epilogue: reduce l over quads, normalize, store fp32 ----
        lsum += __shfl_xor(lsum, 16);
        lsum += __shfl_xor(lsum, 32);
        const int row0 = q_base + wave * 16 + quad * 4;
        #pragma unroll
        for (int r = 0; r < 4; ++r) {
            const float inv = 1.f / __shfl(lsum, quad * 4 + r);  // l lives at lane c16==row
            #pragma unroll
            for (int dt = 0; dt < 4; ++dt)
                Op[(size_t)(row0 + r) * D + dt * 16 + c16] = o[dt][r] * inv;
        }
    }
}

// ---------------------------------------------------------------------------
// Fallback (R2 kernel, proven): used only if ws_size < 32 MB
// ---------------------------------------------------------------------------
__global__ __launch_bounds__(256, 2)
void attn_fwd_fb(const float* __restrict__ Q, const float* __restrict__ K,
                 const float* __restrict__ V, float* __restrict__ O)
{
    constexpr int FSTR = 72;
    constexpr int FQT = 64;
    __shared__ __align__(16) short q_s[FQT * FSTR];
    __shared__ __align__(16) short k_s[64 * FSTR];
    __shared__ __align__(16) short vt_s[E * FSTR];
    __shared__ __align__(16) short p_s[4][16 * FSTR];

    const int tid  = threadIdx.x;
    const int wave = tid >> 6;
    const int lane = tid & 63;
    const int c16  = lane & 15;
    const int quad = lane >> 4;

    const int nqt = L / FQT;
    const int qt  = (nqt - 1) - (int)(blockIdx.x % nqt);
    const int bh  = blockIdx.x / nqt;
    const int b   = bh >> 4;
    const int h   = bh & 15;
    const int q_base = qt * FQT;

    const float* Qp = Q + ((size_t)b * L) * D + h * E;
    const float* Kp = K + ((size_t)b * L) * D + h * E;
    const float* Vp = V + ((size_t)b * L) * D + h * E;
    float*       Op = O + ((size_t)b * L) * D + h * E;

    #pragma unroll
    for (int p = 0; p < 4; ++p) {
        int idx = p * 256 + tid;
        int r = idx >> 4, c4 = (idx & 15) * 4;
        float4 f = *(const float4*)(Qp + (size_t)(q_base + r) * D + c4);
        union { short s[4]; uint2 u; } pk;
        pk.s[0] = bf16_bits(f.x); pk.s[1] = bf16_bits(f.y);
        pk.s[2] = bf16_bits(f.z); pk.s[3] = bf16_bits(f.w);
        *(uint2*)&q_s[r * FSTR + c4] = pk.u;
    }
    __syncthreads();

    short8 qf0 = *(const short8*)&q_s[(wave * 16 + c16) * FSTR + quad * 8];
    short8 qf1 = *(const short8*)&q_s[(wave * 16 + c16) * FSTR + 32 + quad * 8];

    floatx4 o_acc[4];
    #pragma unroll
    for (int nt = 0; nt < 4; ++nt) o_acc[nt] = (floatx4){0.f, 0.f, 0.f, 0.f};
    float m_run[4], l_run[4];
    #pragma unroll
    for (int r = 0; r < 4; ++r) { m_run[r] = -__builtin_inff(); l_run[r] = 0.f; }

    for (int t = 0; t <= qt; ++t) {
        const int k_base = t * 64;
        __syncthreads();
        #pragma unroll
        for (int p = 0; p < 4; ++p) {
            int idx = p * 256 + tid;
            int r = idx >> 4, c4 = (idx & 15) * 4;
            float4 f = *(const float4*)(Kp + (size_t)(k_base + r) * D + c4);
            union { short s[4]; uint2 u; } pk;
            pk.s[0] = bf16_bits(f.x); pk.s[1] = bf16_bits(f.y);
            pk.s[2] = bf16_bits(f.z); pk.s[3] = bf16_bits(f.w);
            *(uint2*)&k_s[r * FSTR + c4] = pk.u;
        }
        #pragma unroll
        for (int p = 0; p < 4; ++p) {
            int s  = lane;
            int dg = p * 4 + wave;
            float4 f = *(const float4*)(Vp + (size_t)(k_base + s) * D + dg * 4);
            vt_s[(dg * 4 + 0) * FSTR + s] = bf16_bits(f.x);
            vt_s[(dg * 4 + 1) * FSTR + s] = bf16_bits(f.y);
            vt_s[(dg * 4 + 2) * FSTR + s] = bf16_bits(f.z);
            vt_s[(dg * 4 + 3) * FSTR + s] = bf16_bits(f.w);
        }
        __syncthreads();

        floatx4 sc[4];
        #pragma unroll
        for (int nt = 0; nt < 4; ++nt) {
            floatx4 acc = (floatx4){0.f, 0.f, 0.f, 0.f};
            short8 b0 = *(const short8*)&k_s[(nt * 16 + c16) * FSTR + quad * 8];
            short8 b1 = *(const short8*)&k_s[(nt * 16 + c16) * FSTR + 32 + quad * 8];
            acc = __builtin_amdgcn_mfma_f32_16x16x32_bf16(qf0, b0, acc, 0, 0, 0);
            acc = __builtin_amdgcn_mfma_f32_16x16x32_bf16(qf1, b1, acc, 0, 0, 0);
            sc[nt] = acc;
        }

        const int q_row0 = q_base + wave * 16 + quad * 4;
        #pragma unroll
        for (int nt = 0; nt < 4; ++nt) {
            const int k_col = k_base + nt * 16 + c16;
            #pragma unroll
            for (int r = 0; r < 4; ++r) {
                float s = sc[nt][r] * SCL_LOG2E;
                sc[nt][r] = (k_col <= q_row0 + r) ? s : -__builtin_inff();
            }
        }

        float alpha[4];
        #pragma unroll
        for (int r = 0; r < 4; ++r) {
            float mx = fmaxf(fmaxf(sc[0][r], sc[1][r]), fmaxf(sc[2][r], sc[3][r]));
            mx = fmaxf(mx, __shfl_xor(mx, 1));
            mx = fmaxf(mx, __shfl_xor(mx, 2));
            mx = fmaxf(mx, __shfl_xor(mx, 4));
            mx = fmaxf(mx, __shfl_xor(mx, 8));
            const float m_new = fmaxf(m_run[r], mx);
            alpha[r] = exp2f(m_run[r] - m_new);
            m_run[r] = m_new;
        }
        float psum[4] = {0.f, 0.f, 0.f, 0.f};
        #pragma unroll
        for (int nt = 0; nt < 4; ++nt) {
            #pragma unroll
            for (int r = 0; r < 4; ++r) {
                float p = exp2f(sc[nt][r] - m_run[r]);
                sc[nt][r] = p;
                psum[r] += p;
            }
        }
        #pragma unroll
        for (int r = 0; r < 4; ++r) {
            float s = psum[r];
            s += __shfl_xor(s, 1);
            s += __shfl_xor(s, 2);
            s += __shfl_xor(s, 4);
            s += __shfl_xor(s, 8);
            l_run[r] = l_run[r] * alpha[r] + s;
            #pragma unroll
            for (int nt = 0; nt < 4; ++nt) o_acc[nt][r] *= alpha[r];
        }

        short* pw = &p_s[wave][0];
        #pragma unroll
        for (int nt = 0; nt < 4; ++nt) {
            #pragma unroll
            for (int r = 0; r < 4; ++r)
                pw[(quad * 4 + r) * FSTR + nt * 16 + c16] = bf16_bits(sc[nt][r]);
        }
        __syncthreads();

        #pragma unroll
        for (int kc = 0; kc < 2; ++kc) {
            short8 pa = *(const short8*)&pw[c16 * FSTR + kc * 32 + quad * 8];
            #pragma unroll
            for (int nt = 0; nt < 4; ++nt) {
                short8 vb = *(const short8*)&vt_s[(nt * 16 + c16) * FSTR + kc * 32 + quad * 8];
                o_acc[nt] = __builtin_amdgcn_mfma_f32_16x16x32_bf16(pa, vb, o_acc[nt], 0, 0, 0);
            }
        }
    }

    const int q_row0 = q_base + wave * 16 + quad * 4;
    #pragma unroll
    for (int r = 0; r < 4; ++r) {
        const float inv_l = 1.f / l_run[r];
        #pragma unroll
        for (int nt = 0; nt < 4; ++nt)
            Op[(size_t)(q_row0 + r) * D + nt * 16 + c16] = o_acc[nt][r] * inv_l;
    }
}

extern "C" void kernel_launch(void* const* d_in, const int* in_sizes, int n_in,
                              void* d_out, int out_size, void* d_ws, size_t ws_size,
                              hipStream_t stream)
{
    const float* Q = (const float*)d_in[0];
    const float* K = (const float*)d_in[1];
    const float* V = (const float*)d_in[2];
    float* O = (float*)d_out;

    const size_t elems = (size_t)B * H * L * E;          // 8M per tensor
    const size_t need  = 2 * elems * sizeof(short);      // 32 MiB

    if (ws_size >= need) {
        short* Kb = (short*)d_ws;
        short* Vt = Kb + elems;
        prep_kv<<<dim3(B * H * 32), dim3(256), 0, stream>>>(K, V, Kb, Vt);
        attn_fwd_p<<<dim3(B * H * 8), dim3(512), 0, stream>>>(Q, Kb, Vt, O);
    } else {
        attn_fwd_fb<<<dim3(B * H * (L / 64)), dim3(256), 0, stream>>>(Q, K, V, O);
    }
}